// Round 1
// baseline (1020.019 us; speedup 1.0000x reference)
//
#include <hip/hip_runtime.h>

#define T_STEPS 1000
#define B_TOT   2048
#define I_IN    40
#define H_N     16
#define TC      25
#define NCHUNK  40
#define EPB     4
#define BLOCK   128
#define CHUNK_FLOATS (EPB*TC*I_IN)   // 4000
#define ELEM_FLOATS  (TC*I_IN)       // 1000
#define LOGITS_OFF 1
#define CORR_OFF  (1 + 2*B_TOT*T_STEPS)   // 4096001
#define TOTAL_OFF (CORR_OFF + 1)          // 4096002

__global__ void snn_init(float* out) {
    out[0] = 0.0f;
    out[CORR_OFF] = 0.0f;
    int cnt = 0;
    for (int t = 0; t < T_STEPS; ++t)
        cnt += ((t > 10) && (((t - 10) % 15) > 5)) ? 1 : 0;
    out[TOTAL_OFF] = (float)cnt * (float)B_TOT;
}

__global__ __launch_bounds__(BLOCK) void snn_main(
    const float* __restrict__ x, const int* __restrict__ target,
    const float* __restrict__ W1, const float* __restrict__ tau_m,
    const float* __restrict__ tau_n, const float* __restrict__ mask,
    const float* __restrict__ W2, const float* __restrict__ b2,
    float* __restrict__ out)
{
    __shared__ float lds[2][CHUNK_FLOATS];
    const int tid = threadIdx.x;
    const int g   = tid >> 5;     // batch elem within block (0..3)
    const int lil = tid & 31;     // row index r = 2n+br
    const int n   = lil >> 1;
    const int br  = lil & 1;
    const int b0  = blockIdx.x * EPB;
    const int b   = b0 + g;

    // masked dendritic weight row, resident in VGPRs
    float w[I_IN];
#pragma unroll
    for (int j = 0; j < I_IN; ++j)
        w[j] = W1[lil*I_IN + j] * mask[lil*I_IN + j];

    const float alpha = 1.0f / (1.0f + __expf(-tau_m[n]));
    const float beta  = 1.0f / (1.0f + __expf(-tau_n[lil]));
    const float w2v   = W2[br*H_N + n];   // even lanes -> logit0 weights, odd -> logit1
    const float b2v0  = b2[0];
    const float b2v1  = b2[1];

    // staging address precompute: thread handles 16B unit u = tid + 128*j
    int  goff[8];
    bool gvalid[8];
#pragma unroll
    for (int j = 0; j < 8; ++j) {
        int u  = tid + BLOCK*j;
        int Lf = u * 4;                       // float index in chunk
        gvalid[j] = (Lf < CHUNK_FLOATS);
        int Lc = gvalid[j] ? Lf : 0;
        int e     = Lc / ELEM_FLOATS;
        int q     = Lc % ELEM_FLOATS;
        int t_off = q / I_IN;
        int i0    = q % I_IN;
        goff[j] = ((b0 + e)*T_STEPS + t_off)*I_IN + i0;
    }

    // prefetch chunk 0
    float4 pf[8];
#pragma unroll
    for (int j = 0; j < 8; ++j)
        if (gvalid[j]) pf[j] = *(const float4*)(x + goff[j]);

    float d_st = 0.0f, mem = 0.0f, spk = 0.0f;
    float acc_loss = 0.0f, acc_corr = 0.0f;
    const bool is_even = (br == 0);

    for (int c = 0; c < NCHUNK; ++c) {
        const int t0 = c * TC;
        float* buf = lds[c & 1];
#pragma unroll
        for (int j = 0; j < 8; ++j)
            if (gvalid[j]) *(float4*)(buf + (tid + BLOCK*j)*4) = pf[j];
        __syncthreads();
        if (c + 1 < NCHUNK) {
            const int tadd = (t0 + TC) * I_IN;
#pragma unroll
            for (int j = 0; j < 8; ++j)
                if (gvalid[j]) pf[j] = *(const float4*)(x + tadd + goff[j]);
        }

        float sL0 = 0.0f, sL1 = 0.0f;
        const float* xg = buf + g*ELEM_FLOATS;
        for (int tt = 0; tt < TC; ++tt) {
            const float4* xv = (const float4*)(xg + tt*I_IN);
            float s0 = 0.f, s1 = 0.f, s2 = 0.f, s3 = 0.f;
#pragma unroll
            for (int j = 0; j < 10; ++j) {
                float4 v = xv[j];
                s0 = fmaf(w[4*j+0], v.x, s0);
                s1 = fmaf(w[4*j+1], v.y, s1);
                s2 = fmaf(w[4*j+2], v.z, s2);
                s3 = fmaf(w[4*j+3], v.w, s3);
            }
            float cur = (s0 + s1) + (s2 + s3);
            // d = beta*d + (1-beta)*cur
            d_st = fmaf(beta, d_st - cur, cur);
            float l = d_st + __shfl_xor(d_st, 1, 64);
            // mem = (mem - spk)*alpha + (1-alpha)*l
            mem = fmaf(alpha, (mem - spk) - l, l);
            spk = (mem > 1.0f) ? 1.0f : 0.0f;
            // logits: parity-preserving butterfly (even lanes sum->logit0, odd->logit1)
            float v2 = spk * w2v;
            v2 += __shfl_xor(v2, 2, 64);
            v2 += __shfl_xor(v2, 4, 64);
            v2 += __shfl_xor(v2, 8, 64);
            v2 += __shfl_xor(v2, 16, 64);
            float oth = __shfl_xor(v2, 1, 64);
            float L0 = (is_even ? v2 : oth) + b2v0;
            float L1 = (is_even ? oth : v2) + b2v1;
            if (lil == tt) { sL0 = L0; sL1 = L1; }   // stash for chunk-end store/CE
        }

        // chunk-end: coalesced logit store + amortized CE (one (b,t) per lane)
        if (lil < TC) {
            const int t = t0 + lil;
            const int oidx = (b*T_STEPS + t)*2;
            out[LOGITS_OFF + oidx]     = sL0;
            out[LOGITS_OFF + oidx + 1] = sL1;
            const bool flag = (t > 10) && (((t - 10) % 15) > 5);
            if (flag) {
                const int tgt = target[b*T_STEPS + t];
                float m   = fmaxf(sL0, sL1);
                float e0  = __expf(sL0 - m), e1 = __expf(sL1 - m);
                float inv = 1.0f / (e0 + e1);
                float p0  = e0*inv, p1 = e1*inv;
                // reference double-softmax: ce = -(p_tgt - logsumexp(p))
                float mm  = fmaxf(p0, p1);
                float lse = mm + __logf(__expf(p0 - mm) + __expf(p1 - mm));
                float qv  = ((tgt == 1) ? p1 : p0) - lse;
                acc_loss -= qv;
                const int pred = (p1 > p0) ? 1 : 0;
                acc_corr += (pred == tgt) ? 1.0f : 0.0f;
            }
        }
    }

    acc_loss *= (1.0f / (float)B_TOT);   // reference ce is mean over batch
#pragma unroll
    for (int mk = 1; mk < 64; mk <<= 1) {
        acc_loss += __shfl_xor(acc_loss, mk, 64);
        acc_corr += __shfl_xor(acc_corr, mk, 64);
    }
    if ((tid & 63) == 0) {
        atomicAdd(out, acc_loss);
        atomicAdd(out + CORR_OFF, acc_corr);
    }
}

extern "C" void kernel_launch(void* const* d_in, const int* in_sizes, int n_in,
                              void* d_out, int out_size, void* d_ws, size_t ws_size,
                              hipStream_t stream) {
    const float* x      = (const float*)d_in[0];
    const int*   target = (const int*)d_in[1];
    const float* W1     = (const float*)d_in[2];
    const float* tau_m  = (const float*)d_in[3];
    const float* tau_n  = (const float*)d_in[4];
    const float* mask   = (const float*)d_in[5];
    const float* W2     = (const float*)d_in[6];
    const float* b2     = (const float*)d_in[7];
    float* out = (float*)d_out;

    snn_init<<<1, 1, 0, stream>>>(out);
    snn_main<<<B_TOT/EPB, BLOCK, 0, stream>>>(x, target, W1, tau_m, tau_n, mask, W2, b2, out);
}

// Round 2
// 861.663 us; speedup vs baseline: 1.1838x; 1.1838x over previous
//
#include <hip/hip_runtime.h>

#define T_STEPS 1000
#define B_TOT   2048
#define I_IN    40
#define H_N     16
#define TC      25
#define NCHUNK  40
#define EPB     4
#define BLOCK   128
#define CHUNK_FLOATS (EPB*TC*I_IN)   // 4000
#define ELEM_FLOATS  (TC*I_IN)       // 1000
#define LOGITS_OFF 1
#define CORR_OFF  (1 + 2*B_TOT*T_STEPS)   // 4096001
#define TOTAL_OFF (CORR_OFF + 1)          // 4096002

__global__ void snn_init(float* out) {
    out[0] = 0.0f;
    out[CORR_OFF] = 0.0f;
    int cnt = 0;
    for (int t = 0; t < T_STEPS; ++t)
        cnt += ((t > 10) && (((t - 10) % 15) > 5)) ? 1 : 0;
    out[TOTAL_OFF] = (float)cnt * (float)B_TOT;
}

// xor-1 neighbor add via DPP quad_perm(1,0,3,2): pure VALU, no LDS latency.
__device__ __forceinline__ float dpp_xor1(float v) {
    int i = __builtin_amdgcn_update_dpp(0, __float_as_int(v), 0xB1, 0xF, 0xF, true);
    return __int_as_float(i);
}

__global__ __launch_bounds__(BLOCK) void snn_main(
    const float* __restrict__ x, const int* __restrict__ target,
    const float* __restrict__ W1, const float* __restrict__ tau_m,
    const float* __restrict__ tau_n, const float* __restrict__ mask,
    const float* __restrict__ W2, const float* __restrict__ b2,
    float* __restrict__ out)
{
    __shared__ float lds[2][CHUNK_FLOATS];
    const int tid = threadIdx.x;
    const int g   = tid >> 5;     // batch elem within block (0..3)
    const int wg  = g & 1;        // which 32-lane half of the wave
    const int lil = tid & 31;     // row index r = 2n+br
    const int n   = lil >> 1;
    const int br  = lil & 1;
    const int b0  = blockIdx.x * EPB;
    const int b   = b0 + g;

    // masked dendritic weight row, resident in VGPRs (order identical to R1)
    float w[I_IN];
#pragma unroll
    for (int j = 0; j < I_IN; ++j)
        w[j] = W1[lil*I_IN + j] * mask[lil*I_IN + j];

    const float alpha = 1.0f / (1.0f + __expf(-tau_m[n]));
    const float beta  = 1.0f / (1.0f + __expf(-tau_n[lil]));
    const float b2v0  = b2[0];
    const float b2v1  = b2[1];

    // W2 rows for logit reconstruction from spike bitmask (uniform -> SGPRs)
    float w20[H_N], w21[H_N];
#pragma unroll
    for (int nn = 0; nn < H_N; ++nn) {
        w20[nn] = W2[nn];
        w21[nn] = W2[H_N + nn];
    }

    // staging address precompute: thread handles 16B unit u = tid + 128*j
    int  goff[8];
    bool gvalid[8];
#pragma unroll
    for (int j = 0; j < 8; ++j) {
        int u  = tid + BLOCK*j;
        int Lf = u * 4;                       // float index in chunk
        gvalid[j] = (Lf < CHUNK_FLOATS);
        int Lc = gvalid[j] ? Lf : 0;
        int e     = Lc / ELEM_FLOATS;
        int q     = Lc % ELEM_FLOATS;
        int t_off = q / I_IN;
        int i0    = q % I_IN;
        goff[j] = ((b0 + e)*T_STEPS + t_off)*I_IN + i0;
    }

    // prefetch chunk 0
    float4 pf[8];
#pragma unroll
    for (int j = 0; j < 8; ++j)
        if (gvalid[j]) pf[j] = *(const float4*)(x + goff[j]);

    float d_st = 0.0f, mem = 0.0f, spk = 0.0f;
    float acc_loss = 0.0f, acc_corr = 0.0f;

    for (int c = 0; c < NCHUNK; ++c) {
        const int t0 = c * TC;
        float* buf = lds[c & 1];
#pragma unroll
        for (int j = 0; j < 8; ++j)
            if (gvalid[j]) *(float4*)(buf + (tid + BLOCK*j)*4) = pf[j];
        __syncthreads();
        if (c + 1 < NCHUNK) {
            const int tadd = (t0 + TC) * I_IN;
#pragma unroll
            for (int j = 0; j < 8; ++j)
                if (gvalid[j]) pf[j] = *(const float4*)(x + tadd + goff[j]);
        }

        unsigned cap_mask = 0u;
        const float* xg = buf + g*ELEM_FLOATS;
#pragma unroll
        for (int tt = 0; tt < TC; ++tt) {
            const float4* xv = (const float4*)(xg + tt*I_IN);
            float s0 = 0.f, s1 = 0.f, s2 = 0.f, s3 = 0.f;
#pragma unroll
            for (int j = 0; j < 10; ++j) {
                float4 v = xv[j];
                s0 = fmaf(w[4*j+0], v.x, s0);
                s1 = fmaf(w[4*j+1], v.y, s1);
                s2 = fmaf(w[4*j+2], v.z, s2);
                s3 = fmaf(w[4*j+3], v.w, s3);
            }
            float cur = (s0 + s1) + (s2 + s3);
            // d = beta*d + (1-beta)*cur
            d_st = fmaf(beta, d_st - cur, cur);
            // l = d0 + d1 via DPP neighbor add (no LDS)
            float l = d_st + dpp_xor1(d_st);
            // mem = (mem - spk)*alpha + (1-alpha)*l
            mem = fmaf(alpha, (mem - spk) - l, l);
            bool fired = (mem > 1.0f);
            spk = fired ? 1.0f : 0.0f;
            // capture this step's spike pattern (16 neurons, bits duplicated at 2n,2n+1)
            unsigned long long bal = __ballot(fired);
            unsigned half = (unsigned)(bal >> (wg * 32));
            if (lil == tt) cap_mask = half;
        }

        // chunk-end: reconstruct logits from spike mask, store + amortized CE
        if (lil < TC) {
            const int t = t0 + lil;
            float sL0 = b2v0, sL1 = b2v1;
#pragma unroll
            for (int nn = 0; nn < H_N; ++nn) {
                float bit = (float)((cap_mask >> (2*nn)) & 1u);
                sL0 = fmaf(bit, w20[nn], sL0);
                sL1 = fmaf(bit, w21[nn], sL1);
            }
            const int oidx = (b*T_STEPS + t)*2;
            out[LOGITS_OFF + oidx]     = sL0;
            out[LOGITS_OFF + oidx + 1] = sL1;
            const bool flag = (t > 10) && (((t - 10) % 15) > 5);
            if (flag) {
                const int tgt = target[b*T_STEPS + t];
                float m   = fmaxf(sL0, sL1);
                float e0  = __expf(sL0 - m), e1 = __expf(sL1 - m);
                float inv = 1.0f / (e0 + e1);
                float p0  = e0*inv, p1 = e1*inv;
                // reference double-softmax: ce = -(p_tgt - logsumexp(p))
                float mm  = fmaxf(p0, p1);
                float lse = mm + __logf(__expf(p0 - mm) + __expf(p1 - mm));
                float qv  = ((tgt == 1) ? p1 : p0) - lse;
                acc_loss -= qv;
                const int pred = (p1 > p0) ? 1 : 0;
                acc_corr += (pred == tgt) ? 1.0f : 0.0f;
            }
        }
    }

    acc_loss *= (1.0f / (float)B_TOT);   // reference ce is mean over batch
#pragma unroll
    for (int mk = 1; mk < 64; mk <<= 1) {
        acc_loss += __shfl_xor(acc_loss, mk, 64);
        acc_corr += __shfl_xor(acc_corr, mk, 64);
    }
    if ((tid & 63) == 0) {
        atomicAdd(out, acc_loss);
        atomicAdd(out + CORR_OFF, acc_corr);
    }
}

extern "C" void kernel_launch(void* const* d_in, const int* in_sizes, int n_in,
                              void* d_out, int out_size, void* d_ws, size_t ws_size,
                              hipStream_t stream) {
    const float* x      = (const float*)d_in[0];
    const int*   target = (const int*)d_in[1];
    const float* W1     = (const float*)d_in[2];
    const float* tau_m  = (const float*)d_in[3];
    const float* tau_n  = (const float*)d_in[4];
    const float* mask   = (const float*)d_in[5];
    const float* W2     = (const float*)d_in[6];
    const float* b2     = (const float*)d_in[7];
    float* out = (float*)d_out;

    snn_init<<<1, 1, 0, stream>>>(out);
    snn_main<<<B_TOT/EPB, BLOCK, 0, stream>>>(x, target, W1, tau_m, tau_n, mask, W2, b2, out);
}

// Round 3
// 560.398 us; speedup vs baseline: 1.8202x; 1.5376x over previous
//
#include <hip/hip_runtime.h>

#define T_STEPS 1000
#define B_TOT   2048
#define I_IN    40
#define H_N     16
#define TC      25
#define NCHUNK  40
#define EPB     2
#define BLOCK   256
#define ELEM_LDS   (TC*48)          // 1200 floats per elem per chunk (12-slot padded quarters)
#define CHUNK_LDS  (EPB*ELEM_LDS)   // 2400 floats
#define NUNIT      (EPB*TC*10)      // 500 float4 units per chunk
#define LOGITS_OFF 1
#define CORR_OFF  (1 + 2*B_TOT*T_STEPS)   // 4096001
#define TOTAL_OFF (CORR_OFF + 1)          // 4096002

__global__ void snn_init(float* out) {
    out[0] = 0.0f;
    out[CORR_OFF] = 0.0f;
    out[TOTAL_OFF] = 1216512.0f;   // 594 flagged steps * 2048 batch
}

// quad_perm DPP helpers: pure VALU cross-lane within groups of 4
__device__ __forceinline__ float dpp_xor1(float v) {
    return __int_as_float(__builtin_amdgcn_update_dpp(0, __float_as_int(v), 0xB1, 0xF, 0xF, true));
}
__device__ __forceinline__ float dpp_xor2(float v) {
    return __int_as_float(__builtin_amdgcn_update_dpp(0, __float_as_int(v), 0x4E, 0xF, 0xF, true));
}
// xor-4 via ds_swizzle BitMode: offset = (xor=4)<<10 | and=0x1F
__device__ __forceinline__ float swz_xor4(float v) {
    return __int_as_float(__builtin_amdgcn_ds_swizzle(__float_as_int(v), 0x101F));
}

__global__ __launch_bounds__(BLOCK) void snn_main(
    const float* __restrict__ x, const int* __restrict__ target,
    const float* __restrict__ W1, const float* __restrict__ tau_m,
    const float* __restrict__ tau_n, const float* __restrict__ mask,
    const float* __restrict__ W2, const float* __restrict__ b2,
    float* __restrict__ out)
{
    __shared__ float xbuf[2][CHUNK_LDS];
    __shared__ unsigned smask[EPB*2*TC];   // [g][h][t] 8-bit spike masks

    const int tid  = threadIdx.x;
    const int g    = tid >> 7;        // batch elem within block (0..1)
    const int lane = tid & 63;
    const int h    = (tid >> 6) & 1;  // which wave of the elem (neurons 0-7 / 8-15)
    const int q    = lane & 3;        // residue class (stride-4 split of the dot product)
    const int br   = (lane >> 2) & 1; // branch
    const int nl   = lane >> 3;       // neuron-local 0..7
    const int n    = h*8 + nl;        // neuron 0..15
    const int r    = n*2 + br;        // dendritic row 0..31
    const int b0   = blockIdx.x * EPB;

    // lane's residue-class weights: w[j] = Wm[r][4j+q], j=0..9 (same accumulation order as R1/R2)
    float w[10];
#pragma unroll
    for (int j = 0; j < 10; ++j) {
        const int i = 4*j + q;
        w[j] = W1[r*I_IN + i] * mask[r*I_IN + i];
    }

    const float alpha = 1.0f / (1.0f + __expf(-tau_m[n]));
    const float beta  = 1.0f / (1.0f + __expf(-tau_n[r]));
    const float b2v0  = b2[0];
    const float b2v1  = b2[1];

    float w20[H_N], w21[H_N];
#pragma unroll
    for (int nn = 0; nn < H_N; ++nn) {
        w20[nn] = W2[nn];
        w21[nn] = W2[H_N + nn];
    }

    // staging: unit u covers x[(b0+e), t0+tf, 4*f4 .. 4*f4+4), scattered into [t][q][12] layout
    int goff0, lds0, goff1 = 0, lds1 = 0;
    const bool v1ok = (tid + BLOCK) < NUNIT;
    {
        const int u = tid, e = u/250, rem = u%250, tf = rem/10, f4 = rem%10;
        goff0 = ((b0+e)*T_STEPS + tf)*I_IN + 4*f4;
        lds0  = e*ELEM_LDS + tf*48 + f4;
    }
    if (v1ok) {
        const int u = tid + BLOCK, e = u/250, rem = u%250, tf = rem/10, f4 = rem%10;
        goff1 = ((b0+e)*T_STEPS + tf)*I_IN + 4*f4;
        lds1  = e*ELEM_LDS + tf*48 + f4;
    }

    float4 pf0 = *(const float4*)(x + goff0);
    float4 pf1 = v1ok ? *(const float4*)(x + goff1) : make_float4(0,0,0,0);

    // combine-role assignment: 50 lanes spread across all 4 waves
    const int  p    = tid >> 2;
    const bool comb = ((tid & 3) == 0) && (p < EPB*TC);
    const int  cg   = p / TC, ct = p % TC;

    float d_st = 0.0f, mem = 0.0f, spk = 0.0f;
    float acc_loss = 0.0f, acc_corr = 0.0f;
    unsigned long long cap = 0;

    for (int c = 0; c < NCHUNK; ++c) {
        const int t0 = c * TC;
        float* buf = xbuf[c & 1];
        // transpose-scatter staged data: component k -> quarter slot k*12
        buf[lds0] = pf0.x; buf[lds0+12] = pf0.y; buf[lds0+24] = pf0.z; buf[lds0+36] = pf0.w;
        if (v1ok) { buf[lds1] = pf1.x; buf[lds1+12] = pf1.y; buf[lds1+24] = pf1.z; buf[lds1+36] = pf1.w; }
        __syncthreads();
        if (c + 1 < NCHUNK) {
            const int tadd = (t0 + TC) * I_IN;
            pf0 = *(const float4*)(x + tadd + goff0);
            if (v1ok) pf1 = *(const float4*)(x + tadd + goff1);
        }

        const float* xg = buf + g*ELEM_LDS + q*12;
#pragma unroll
        for (int tt = 0; tt < TC; ++tt) {
            const float* xp = xg + tt*48;
            const float4 a0 = *(const float4*)(xp);
            const float4 a1 = *(const float4*)(xp + 4);
            const float2 a2 = *(const float2*)(xp + 8);
            float s = 0.0f;                       // s_q, accumulated in R1's j order
            s = fmaf(w[0], a0.x, s); s = fmaf(w[1], a0.y, s);
            s = fmaf(w[2], a0.z, s); s = fmaf(w[3], a0.w, s);
            s = fmaf(w[4], a1.x, s); s = fmaf(w[5], a1.y, s);
            s = fmaf(w[6], a1.z, s); s = fmaf(w[7], a1.w, s);
            s = fmaf(w[8], a2.x, s); s = fmaf(w[9], a2.y, s);
            const float s01 = s + dpp_xor1(s);    // (s0+s1) / (s2+s3)
            const float cur = s01 + dpp_xor2(s01);// (s0+s1)+(s2+s3): bit-exact R1 order
            d_st = fmaf(beta, d_st - cur, cur);
            const float l = d_st + swz_xor4(d_st);
            mem = fmaf(alpha, (mem - spk) - l, l);
            const bool fired = mem > 1.0f;
            spk = fired ? 1.0f : 0.0f;
            const unsigned long long bal = __ballot(fired);
            if (lane == tt) cap = bal;
        }

        // publish 8-bit spike masks (bit k = neuron h*8+k, from lane k*8 of the ballot)
        if (lane < TC) {
            unsigned m8 = 0;
#pragma unroll
            for (int k = 0; k < 8; ++k)
                m8 |= ((unsigned)(cap >> (k*8)) & 1u) << k;
            smask[(g*2 + h)*TC + lane] = m8;
        }
        __syncthreads();

        if (comb) {
            const int t = t0 + ct;
            const unsigned m = smask[(cg*2 + 0)*TC + ct] | (smask[(cg*2 + 1)*TC + ct] << 8);
            float sL0 = b2v0, sL1 = b2v1;
#pragma unroll
            for (int nn = 0; nn < H_N; ++nn) {     // same fma order as R2 -> bit-exact logits
                const float f = (float)((m >> nn) & 1u);
                sL0 = fmaf(f, w20[nn], sL0);
                sL1 = fmaf(f, w21[nn], sL1);
            }
            const int b = b0 + cg;
            const int oidx = (b*T_STEPS + t)*2;
            out[LOGITS_OFF + oidx]     = sL0;
            out[LOGITS_OFF + oidx + 1] = sL1;
            const bool flag = (t > 10) && (((t - 10) % 15) > 5);
            if (flag) {
                const int tgt = target[b*T_STEPS + t];
                float mx  = fmaxf(sL0, sL1);
                float e0  = __expf(sL0 - mx), e1 = __expf(sL1 - mx);
                float inv = 1.0f / (e0 + e1);
                float p0  = e0*inv, p1 = e1*inv;
                float mm  = fmaxf(p0, p1);
                float lse = mm + __logf(__expf(p0 - mm) + __expf(p1 - mm));
                float qv  = ((tgt == 1) ? p1 : p0) - lse;
                acc_loss -= qv;
                const int pred = (p1 > p0) ? 1 : 0;
                acc_corr += (pred == tgt) ? 1.0f : 0.0f;
            }
        }
    }

    acc_loss *= (1.0f / (float)B_TOT);
#pragma unroll
    for (int mk = 1; mk < 64; mk <<= 1) {
        acc_loss += __shfl_xor(acc_loss, mk, 64);
        acc_corr += __shfl_xor(acc_corr, mk, 64);
    }
    if (lane == 0) {
        atomicAdd(out, acc_loss);
        atomicAdd(out + CORR_OFF, acc_corr);
    }
}

extern "C" void kernel_launch(void* const* d_in, const int* in_sizes, int n_in,
                              void* d_out, int out_size, void* d_ws, size_t ws_size,
                              hipStream_t stream) {
    const float* x      = (const float*)d_in[0];
    const int*   target = (const int*)d_in[1];
    const float* W1     = (const float*)d_in[2];
    const float* tau_m  = (const float*)d_in[3];
    const float* tau_n  = (const float*)d_in[4];
    const float* mask   = (const float*)d_in[5];
    const float* W2     = (const float*)d_in[6];
    const float* b2     = (const float*)d_in[7];
    float* out = (float*)d_out;

    snn_init<<<1, 1, 0, stream>>>(out);
    snn_main<<<B_TOT/EPB, BLOCK, 0, stream>>>(x, target, W1, tau_m, tau_n, mask, W2, b2, out);
}